// Round 1
// baseline (1229.308 us; speedup 1.0000x reference)
//
#include <hip/hip_runtime.h>
#include <hip/hip_bf16.h>
#include <math.h>

#define N_NODES 100000
#define N_EDGES 1600000
#define HID 128
#define N_CLASS 10

// ---------------------------------------------------------------------------
// CSR build: histogram -> hierarchical exclusive scan -> fill
// ---------------------------------------------------------------------------

__global__ void count_k(const int* __restrict__ dst, int* __restrict__ cnt) {
    int e = blockIdx.x * blockDim.x + threadIdx.x;
    if (e < N_EDGES) atomicAdd(&cnt[dst[e]], 1);
}

// 256 threads x 4 elems = 1024 elems/block
__global__ void scan1_k(const int* __restrict__ in, int* __restrict__ out,
                        int* __restrict__ bsum) {
    __shared__ int sh[256];
    int base = blockIdx.x * 1024 + threadIdx.x * 4;
    int v[4];
    int s = 0;
#pragma unroll
    for (int i = 0; i < 4; i++) {
        int idx = base + i;
        v[i] = (idx < N_NODES) ? in[idx] : 0;
        s += v[i];
    }
    sh[threadIdx.x] = s;
    __syncthreads();
    for (int off = 1; off < 256; off <<= 1) {
        int t = (threadIdx.x >= off) ? sh[threadIdx.x - off] : 0;
        __syncthreads();
        sh[threadIdx.x] += t;
        __syncthreads();
    }
    int excl = sh[threadIdx.x] - s;
    if (threadIdx.x == 255) bsum[blockIdx.x] = sh[255];
    int run = excl;
#pragma unroll
    for (int i = 0; i < 4; i++) {
        int idx = base + i;
        if (idx < N_NODES) out[idx] = run;
        run += v[i];
    }
}

__global__ void scan2_k(int* __restrict__ bsum, int nb) {
    __shared__ int sh[256];
    int v = (threadIdx.x < nb) ? bsum[threadIdx.x] : 0;
    sh[threadIdx.x] = v;
    __syncthreads();
    for (int off = 1; off < 256; off <<= 1) {
        int t = (threadIdx.x >= off) ? sh[threadIdx.x - off] : 0;
        __syncthreads();
        sh[threadIdx.x] += t;
        __syncthreads();
    }
    if (threadIdx.x < nb) bsum[threadIdx.x] = sh[threadIdx.x] - v;  // exclusive
}

__global__ void scan3_k(int* __restrict__ row_ptr, const int* __restrict__ bsum,
                        int* __restrict__ cursor) {
    int i = blockIdx.x * blockDim.x + threadIdx.x;
    if (i < N_NODES) {
        int v = row_ptr[i] + bsum[i >> 10];
        row_ptr[i] = v;
        cursor[i] = v;
    }
    if (i == 0) row_ptr[N_NODES] = N_EDGES;
}

__global__ void fill_k(const int* __restrict__ src, const int* __restrict__ dst,
                       int* __restrict__ cursor, int* __restrict__ col) {
    int e = blockIdx.x * blockDim.x + threadIdx.x;
    if (e < N_EDGES) {
        int d = dst[e];
        int slot = atomicAdd(&cursor[d], 1);
        col[slot] = src[e];
    }
}

// ---------------------------------------------------------------------------
// Aggregation: one wave per node, lane holds float2 of the 128-dim row.
// z[n] = h[n] + sum_{s in N(n)} h[s]
// ---------------------------------------------------------------------------
__global__ __launch_bounds__(256) void agg_k(const float* __restrict__ h,
                                             const int* __restrict__ row_ptr,
                                             const int* __restrict__ col,
                                             float* __restrict__ z) {
    int wave = (blockIdx.x * blockDim.x + threadIdx.x) >> 6;
    int lane = threadIdx.x & 63;
    if (wave >= N_NODES) return;
    const float2* hp = (const float2*)h;
    float2 acc = hp[(size_t)wave * 64 + lane];  // self term, (1+eps)=1
    int beg = row_ptr[wave];
    int end = row_ptr[wave + 1];
    for (int i = beg; i < end; i++) {
        int s = col[i];
        float2 v = hp[(size_t)s * 64 + lane];
        acc.x += v.x;
        acc.y += v.y;
    }
    ((float2*)z)[(size_t)wave * 64 + lane] = acc;
}

// ---------------------------------------------------------------------------
// Fused 2-layer MLP with ELU: h_out = ELU(ELU(z@Wa + ba)@Wb + bb)
// 32 nodes per block, z & t tiles in LDS, weights via L1/L2 broadcast.
// In-place safe: block only reads/writes its own 32 rows.
// ---------------------------------------------------------------------------
__device__ __forceinline__ float elu(float x) {
    return x > 0.f ? x : (expf(x) - 1.f);
}

__global__ __launch_bounds__(256) void mlp_k(const float* __restrict__ zin,
                                             const float* __restrict__ Wa,
                                             const float* __restrict__ ba,
                                             const float* __restrict__ Wb,
                                             const float* __restrict__ bb,
                                             float* __restrict__ hout) {
    __shared__ float zt[32][HID];
    __shared__ float tt[32][HID];
    const int tid = threadIdx.x;
    const int lane = tid & 63;
    const int wid = tid >> 6;
    const int j0 = lane * 2;
    const size_t node_base = (size_t)blockIdx.x * 32;

    // cooperative load of 32x128 z tile (4 float4 per thread)
#pragma unroll
    for (int r = 0; r < 4; r++) {
        int off = r * 1024 + tid * 4;
        *(float4*)&zt[0][off] = *(const float4*)&zin[node_base * HID + off];
    }
    __syncthreads();

    // phase 1: t = ELU(z @ Wa + ba)
    {
        float acc[8][2];
        float b0 = ba[j0], b1 = ba[j0 + 1];
#pragma unroll
        for (int i = 0; i < 8; i++) { acc[i][0] = b0; acc[i][1] = b1; }
        for (int k = 0; k < HID; k += 4) {
            float2 w0 = *(const float2*)&Wa[(k + 0) * HID + j0];
            float2 w1 = *(const float2*)&Wa[(k + 1) * HID + j0];
            float2 w2 = *(const float2*)&Wa[(k + 2) * HID + j0];
            float2 w3 = *(const float2*)&Wa[(k + 3) * HID + j0];
#pragma unroll
            for (int i = 0; i < 8; i++) {
                const float4 zv = *(const float4*)&zt[wid + 4 * i][k];
                acc[i][0] += zv.x * w0.x + zv.y * w1.x + zv.z * w2.x + zv.w * w3.x;
                acc[i][1] += zv.x * w0.y + zv.y * w1.y + zv.z * w2.y + zv.w * w3.y;
            }
        }
#pragma unroll
        for (int i = 0; i < 8; i++) {
            int n = wid + 4 * i;
            tt[n][j0] = elu(acc[i][0]);
            tt[n][j0 + 1] = elu(acc[i][1]);
        }
    }
    __syncthreads();

    // phase 2: h = ELU(t @ Wb + bb)
    {
        float acc[8][2];
        float b0 = bb[j0], b1 = bb[j0 + 1];
#pragma unroll
        for (int i = 0; i < 8; i++) { acc[i][0] = b0; acc[i][1] = b1; }
        for (int k = 0; k < HID; k += 4) {
            float2 w0 = *(const float2*)&Wb[(k + 0) * HID + j0];
            float2 w1 = *(const float2*)&Wb[(k + 1) * HID + j0];
            float2 w2 = *(const float2*)&Wb[(k + 2) * HID + j0];
            float2 w3 = *(const float2*)&Wb[(k + 3) * HID + j0];
#pragma unroll
            for (int i = 0; i < 8; i++) {
                const float4 zv = *(const float4*)&tt[wid + 4 * i][k];
                acc[i][0] += zv.x * w0.x + zv.y * w1.x + zv.z * w2.x + zv.w * w3.x;
                acc[i][1] += zv.x * w0.y + zv.y * w1.y + zv.z * w2.y + zv.w * w3.y;
            }
        }
#pragma unroll
        for (int i = 0; i < 8; i++) {
            size_t n = node_base + wid + 4 * i;
            float2 o;
            o.x = elu(acc[i][0]);
            o.y = elu(acc[i][1]);
            *(float2*)&hout[n * HID + j0] = o;
        }
    }
}

// ---------------------------------------------------------------------------
// Final FC: out = h @ fcW + fcb   [100k x 10]
// ---------------------------------------------------------------------------
__global__ __launch_bounds__(256) void fc_k(const float* __restrict__ h,
                                            const float* __restrict__ fcW,
                                            const float* __restrict__ fcb,
                                            float* __restrict__ out) {
    __shared__ float ht[64][HID + 4];  // pad to break bank conflicts
    size_t nb = (size_t)blockIdx.x * 64;
#pragma unroll
    for (int r = 0; r < 8; r++) {
        int off = r * 1024 + threadIdx.x * 4;
        int row = off >> 7, colo = off & 127;
        if (nb + row < N_NODES)
            *(float4*)&ht[row][colo] = *(const float4*)&h[(nb + row) * HID + colo];
    }
    __syncthreads();
    for (int o = threadIdx.x; o < 64 * N_CLASS; o += 256) {
        int n = o / N_CLASS, c = o % N_CLASS;
        if (nb + n < N_NODES) {
            float acc = fcb[c];
            for (int k = 0; k < HID; k++) acc += ht[n][k] * fcW[k * N_CLASS + c];
            out[(nb + n) * N_CLASS + c] = acc;
        }
    }
}

// ---------------------------------------------------------------------------

extern "C" void kernel_launch(void* const* d_in, const int* in_sizes, int n_in,
                              void* d_out, int out_size, void* d_ws, size_t ws_size,
                              hipStream_t stream) {
    const float* x = (const float*)d_in[0];
    const int* ei = (const int*)d_in[1];  // [2][E]
    // d_in[2] = edge_weight (unused by the reference forward)
    const float* Wa = (const float*)d_in[3];   // [3][128][128]
    const float* ba = (const float*)d_in[4];   // [3][128]
    const float* Wb = (const float*)d_in[5];
    const float* bb = (const float*)d_in[6];
    const float* fcW = (const float*)d_in[7];  // [128][10]
    const float* fcb = (const float*)d_in[8];  // [10]
    float* out = (float*)d_out;

    const int* src = ei;
    const int* dst = ei + N_EDGES;

    // workspace carve
    char* w = (char*)d_ws;
    float* bufA = (float*)w; w += (size_t)N_NODES * HID * 4;
    float* bufB = (float*)w; w += (size_t)N_NODES * HID * 4;
    int* row_ptr = (int*)w;  w += ((size_t)N_NODES + 8) * 4;
    int* cursor = (int*)w;   w += (size_t)N_NODES * 4;
    int* col = (int*)w;      w += (size_t)N_EDGES * 4;
    int* bsum = (int*)w;     w += 256 * 4;

    const int SCAN_BLOCKS = (N_NODES + 1023) / 1024;  // 98

    // ---- CSR build ----
    hipMemsetAsync(cursor, 0, (size_t)N_NODES * 4, stream);
    count_k<<<N_EDGES / 256, 256, 0, stream>>>(dst, cursor);
    scan1_k<<<SCAN_BLOCKS, 256, 0, stream>>>(cursor, row_ptr, bsum);
    scan2_k<<<1, 256, 0, stream>>>(bsum, SCAN_BLOCKS);
    scan3_k<<<(N_NODES + 255) / 256, 256, 0, stream>>>(row_ptr, bsum, cursor);
    fill_k<<<N_EDGES / 256, 256, 0, stream>>>(src, dst, cursor, col);

    const int AGG_BLOCKS = N_NODES * 64 / 256;  // one wave per node
    const int MLP_BLOCKS = N_NODES / 32;

    // ---- layer 1: x -> bufB ----
    agg_k<<<AGG_BLOCKS, 256, 0, stream>>>(x, row_ptr, col, bufB);
    mlp_k<<<MLP_BLOCKS, 256, 0, stream>>>(bufB, Wa, ba, Wb, bb, bufB);
    // ---- layer 2: bufB -> bufA ----
    agg_k<<<AGG_BLOCKS, 256, 0, stream>>>(bufB, row_ptr, col, bufA);
    mlp_k<<<MLP_BLOCKS, 256, 0, stream>>>(bufA, Wa + 16384, ba + 128,
                                          Wb + 16384, bb + 128, bufA);
    // ---- layer 3: bufA -> bufB ----
    agg_k<<<AGG_BLOCKS, 256, 0, stream>>>(bufA, row_ptr, col, bufB);
    mlp_k<<<MLP_BLOCKS, 256, 0, stream>>>(bufB, Wa + 32768, ba + 256,
                                          Wb + 32768, bb + 256, bufB);
    // ---- final FC ----
    fc_k<<<(N_NODES + 63) / 64, 256, 0, stream>>>(bufB, fcW, fcb, out);
}

// Round 2
// 1073.794 us; speedup vs baseline: 1.1448x; 1.1448x over previous
//
#include <hip/hip_runtime.h>
#include <hip/hip_bf16.h>
#include <math.h>

#define N_NODES 100000
#define N_EDGES 1600000
#define HID 128
#define N_CLASS 10

// ---------------------------------------------------------------------------
// CSR build: histogram -> hierarchical exclusive scan -> fill
// ---------------------------------------------------------------------------

__global__ void count_k(const int* __restrict__ dst, int* __restrict__ cnt) {
    int e = blockIdx.x * blockDim.x + threadIdx.x;
    if (e < N_EDGES) atomicAdd(&cnt[dst[e]], 1);
}

// 256 threads x 4 elems = 1024 elems/block
__global__ void scan1_k(const int* __restrict__ in, int* __restrict__ out,
                        int* __restrict__ bsum) {
    __shared__ int sh[256];
    int base = blockIdx.x * 1024 + threadIdx.x * 4;
    int v[4];
    int s = 0;
#pragma unroll
    for (int i = 0; i < 4; i++) {
        int idx = base + i;
        v[i] = (idx < N_NODES) ? in[idx] : 0;
        s += v[i];
    }
    sh[threadIdx.x] = s;
    __syncthreads();
    for (int off = 1; off < 256; off <<= 1) {
        int t = (threadIdx.x >= off) ? sh[threadIdx.x - off] : 0;
        __syncthreads();
        sh[threadIdx.x] += t;
        __syncthreads();
    }
    int excl = sh[threadIdx.x] - s;
    if (threadIdx.x == 255) bsum[blockIdx.x] = sh[255];
    int run = excl;
#pragma unroll
    for (int i = 0; i < 4; i++) {
        int idx = base + i;
        if (idx < N_NODES) out[idx] = run;
        run += v[i];
    }
}

__global__ void scan2_k(int* __restrict__ bsum, int nb) {
    __shared__ int sh[256];
    int v = (threadIdx.x < nb) ? bsum[threadIdx.x] : 0;
    sh[threadIdx.x] = v;
    __syncthreads();
    for (int off = 1; off < 256; off <<= 1) {
        int t = (threadIdx.x >= off) ? sh[threadIdx.x - off] : 0;
        __syncthreads();
        sh[threadIdx.x] += t;
        __syncthreads();
    }
    if (threadIdx.x < nb) bsum[threadIdx.x] = sh[threadIdx.x] - v;  // exclusive
}

__global__ void scan3_k(int* __restrict__ row_ptr, const int* __restrict__ bsum,
                        int* __restrict__ cursor) {
    int i = blockIdx.x * blockDim.x + threadIdx.x;
    if (i < N_NODES) {
        int v = row_ptr[i] + bsum[i >> 10];
        row_ptr[i] = v;
        cursor[i] = v;
    }
    if (i == 0) row_ptr[N_NODES] = N_EDGES;
}

__global__ void fill_k(const int* __restrict__ src, const int* __restrict__ dst,
                       int* __restrict__ cursor, int* __restrict__ col) {
    int e = blockIdx.x * blockDim.x + threadIdx.x;
    if (e < N_EDGES) {
        int d = dst[e];
        int slot = atomicAdd(&cursor[d], 1);
        col[slot] = src[e];
    }
}

// ---------------------------------------------------------------------------
// Aggregation v2: one HALF-WAVE (32 lanes) per node, float4 per lane
// (32 x 16B = one 512B row). Neighbor indices batch-preloaded (one coalesced
// load per 32 edges) and broadcast in-register via __shfl, gathers unrolled
// x4 for memory-level parallelism.
// z[n] = h[n] + sum_{s in N(n)} h[s]
// ---------------------------------------------------------------------------
__global__ __launch_bounds__(256) void agg_k(const float* __restrict__ h,
                                             const int* __restrict__ row_ptr,
                                             const int* __restrict__ col,
                                             float* __restrict__ z) {
    const int half = (blockIdx.x * blockDim.x + threadIdx.x) >> 5;  // node id
    const int lane = threadIdx.x & 31;
    const int halfbase = threadIdx.x & 32;  // lane offset of this half-wave
    if (half >= N_NODES) return;
    const float4* hp = (const float4*)h;
    float4 acc = hp[(size_t)half * 32 + lane];  // self term, (1+eps)=1
    const int beg = row_ptr[half];
    const int end = row_ptr[half + 1];

    for (int base = beg; base < end; base += 32) {
        const int n = min(32, end - base);
        int myidx = (lane < n) ? col[base + lane] : 0;
        int j = 0;
        for (; j + 4 <= n; j += 4) {
            int i0 = __shfl(myidx, halfbase + j + 0, 64);
            int i1 = __shfl(myidx, halfbase + j + 1, 64);
            int i2 = __shfl(myidx, halfbase + j + 2, 64);
            int i3 = __shfl(myidx, halfbase + j + 3, 64);
            float4 v0 = hp[(size_t)i0 * 32 + lane];
            float4 v1 = hp[(size_t)i1 * 32 + lane];
            float4 v2 = hp[(size_t)i2 * 32 + lane];
            float4 v3 = hp[(size_t)i3 * 32 + lane];
            acc.x += v0.x; acc.y += v0.y; acc.z += v0.z; acc.w += v0.w;
            acc.x += v1.x; acc.y += v1.y; acc.z += v1.z; acc.w += v1.w;
            acc.x += v2.x; acc.y += v2.y; acc.z += v2.z; acc.w += v2.w;
            acc.x += v3.x; acc.y += v3.y; acc.z += v3.z; acc.w += v3.w;
        }
        for (; j < n; j++) {
            int i0 = __shfl(myidx, halfbase + j, 64);
            float4 v0 = hp[(size_t)i0 * 32 + lane];
            acc.x += v0.x; acc.y += v0.y; acc.z += v0.z; acc.w += v0.w;
        }
    }
    ((float4*)z)[(size_t)half * 32 + lane] = acc;
}

// ---------------------------------------------------------------------------
// Fused 2-layer MLP with ELU: h_out = ELU(ELU(z@Wa + ba)@Wb + bb)
// 32 nodes per block, z & t tiles in LDS, weights via L1/L2 broadcast.
// In-place safe: block only reads/writes its own 32 rows.
// ---------------------------------------------------------------------------
__device__ __forceinline__ float elu(float x) {
    return x > 0.f ? x : (expf(x) - 1.f);
}

__global__ __launch_bounds__(256) void mlp_k(const float* __restrict__ zin,
                                             const float* __restrict__ Wa,
                                             const float* __restrict__ ba,
                                             const float* __restrict__ Wb,
                                             const float* __restrict__ bb,
                                             float* __restrict__ hout) {
    __shared__ float zt[32][HID];
    __shared__ float tt[32][HID];
    const int tid = threadIdx.x;
    const int lane = tid & 63;
    const int wid = tid >> 6;
    const int j0 = lane * 2;
    const size_t node_base = (size_t)blockIdx.x * 32;

    // cooperative load of 32x128 z tile (4 float4 per thread)
#pragma unroll
    for (int r = 0; r < 4; r++) {
        int off = r * 1024 + tid * 4;
        *(float4*)&zt[0][off] = *(const float4*)&zin[node_base * HID + off];
    }
    __syncthreads();

    // phase 1: t = ELU(z @ Wa + ba)
    {
        float acc[8][2];
        float b0 = ba[j0], b1 = ba[j0 + 1];
#pragma unroll
        for (int i = 0; i < 8; i++) { acc[i][0] = b0; acc[i][1] = b1; }
        for (int k = 0; k < HID; k += 4) {
            float2 w0 = *(const float2*)&Wa[(k + 0) * HID + j0];
            float2 w1 = *(const float2*)&Wa[(k + 1) * HID + j0];
            float2 w2 = *(const float2*)&Wa[(k + 2) * HID + j0];
            float2 w3 = *(const float2*)&Wa[(k + 3) * HID + j0];
#pragma unroll
            for (int i = 0; i < 8; i++) {
                const float4 zv = *(const float4*)&zt[wid + 4 * i][k];
                acc[i][0] += zv.x * w0.x + zv.y * w1.x + zv.z * w2.x + zv.w * w3.x;
                acc[i][1] += zv.x * w0.y + zv.y * w1.y + zv.z * w2.y + zv.w * w3.y;
            }
        }
#pragma unroll
        for (int i = 0; i < 8; i++) {
            int n = wid + 4 * i;
            tt[n][j0] = elu(acc[i][0]);
            tt[n][j0 + 1] = elu(acc[i][1]);
        }
    }
    __syncthreads();

    // phase 2: h = ELU(t @ Wb + bb)
    {
        float acc[8][2];
        float b0 = bb[j0], b1 = bb[j0 + 1];
#pragma unroll
        for (int i = 0; i < 8; i++) { acc[i][0] = b0; acc[i][1] = b1; }
        for (int k = 0; k < HID; k += 4) {
            float2 w0 = *(const float2*)&Wb[(k + 0) * HID + j0];
            float2 w1 = *(const float2*)&Wb[(k + 1) * HID + j0];
            float2 w2 = *(const float2*)&Wb[(k + 2) * HID + j0];
            float2 w3 = *(const float2*)&Wb[(k + 3) * HID + j0];
#pragma unroll
            for (int i = 0; i < 8; i++) {
                const float4 zv = *(const float4*)&tt[wid + 4 * i][k];
                acc[i][0] += zv.x * w0.x + zv.y * w1.x + zv.z * w2.x + zv.w * w3.x;
                acc[i][1] += zv.x * w0.y + zv.y * w1.y + zv.z * w2.y + zv.w * w3.y;
            }
        }
#pragma unroll
        for (int i = 0; i < 8; i++) {
            size_t n = node_base + wid + 4 * i;
            float2 o;
            o.x = elu(acc[i][0]);
            o.y = elu(acc[i][1]);
            *(float2*)&hout[n * HID + j0] = o;
        }
    }
}

// ---------------------------------------------------------------------------
// Final FC: out = h @ fcW + fcb   [100k x 10]
// ---------------------------------------------------------------------------
__global__ __launch_bounds__(256) void fc_k(const float* __restrict__ h,
                                            const float* __restrict__ fcW,
                                            const float* __restrict__ fcb,
                                            float* __restrict__ out) {
    __shared__ float ht[64][HID + 4];  // pad to break bank conflicts
    size_t nb = (size_t)blockIdx.x * 64;
#pragma unroll
    for (int r = 0; r < 8; r++) {
        int off = r * 1024 + threadIdx.x * 4;
        int row = off >> 7, colo = off & 127;
        if (nb + row < N_NODES)
            *(float4*)&ht[row][colo] = *(const float4*)&h[(nb + row) * HID + colo];
    }
    __syncthreads();
    for (int o = threadIdx.x; o < 64 * N_CLASS; o += 256) {
        int n = o / N_CLASS, c = o % N_CLASS;
        if (nb + n < N_NODES) {
            float acc = fcb[c];
            for (int k = 0; k < HID; k++) acc += ht[n][k] * fcW[k * N_CLASS + c];
            out[(nb + n) * N_CLASS + c] = acc;
        }
    }
}

// ---------------------------------------------------------------------------

extern "C" void kernel_launch(void* const* d_in, const int* in_sizes, int n_in,
                              void* d_out, int out_size, void* d_ws, size_t ws_size,
                              hipStream_t stream) {
    const float* x = (const float*)d_in[0];
    const int* ei = (const int*)d_in[1];  // [2][E]
    // d_in[2] = edge_weight (unused by the reference forward)
    const float* Wa = (const float*)d_in[3];   // [3][128][128]
    const float* ba = (const float*)d_in[4];   // [3][128]
    const float* Wb = (const float*)d_in[5];
    const float* bb = (const float*)d_in[6];
    const float* fcW = (const float*)d_in[7];  // [128][10]
    const float* fcb = (const float*)d_in[8];  // [10]
    float* out = (float*)d_out;

    const int* src = ei;
    const int* dst = ei + N_EDGES;

    // workspace carve
    char* w = (char*)d_ws;
    float* bufA = (float*)w; w += (size_t)N_NODES * HID * 4;
    float* bufB = (float*)w; w += (size_t)N_NODES * HID * 4;
    int* row_ptr = (int*)w;  w += ((size_t)N_NODES + 8) * 4;
    int* cursor = (int*)w;   w += (size_t)N_NODES * 4;
    int* col = (int*)w;      w += (size_t)N_EDGES * 4;
    int* bsum = (int*)w;     w += 256 * 4;

    const int SCAN_BLOCKS = (N_NODES + 1023) / 1024;  // 98

    // ---- CSR build ----
    hipMemsetAsync(cursor, 0, (size_t)N_NODES * 4, stream);
    count_k<<<N_EDGES / 256, 256, 0, stream>>>(dst, cursor);
    scan1_k<<<SCAN_BLOCKS, 256, 0, stream>>>(cursor, row_ptr, bsum);
    scan2_k<<<1, 256, 0, stream>>>(bsum, SCAN_BLOCKS);
    scan3_k<<<(N_NODES + 255) / 256, 256, 0, stream>>>(row_ptr, bsum, cursor);
    fill_k<<<N_EDGES / 256, 256, 0, stream>>>(src, dst, cursor, col);

    const int AGG_BLOCKS = (N_NODES * 32 + 255) / 256;  // one half-wave per node
    const int MLP_BLOCKS = N_NODES / 32;

    // ---- layer 1: x -> bufB ----
    agg_k<<<AGG_BLOCKS, 256, 0, stream>>>(x, row_ptr, col, bufB);
    mlp_k<<<MLP_BLOCKS, 256, 0, stream>>>(bufB, Wa, ba, Wb, bb, bufB);
    // ---- layer 2: bufB -> bufA ----
    agg_k<<<AGG_BLOCKS, 256, 0, stream>>>(bufB, row_ptr, col, bufA);
    mlp_k<<<MLP_BLOCKS, 256, 0, stream>>>(bufA, Wa + 16384, ba + 128,
                                          Wb + 16384, bb + 128, bufA);
    // ---- layer 3: bufA -> bufB ----
    agg_k<<<AGG_BLOCKS, 256, 0, stream>>>(bufA, row_ptr, col, bufB);
    mlp_k<<<MLP_BLOCKS, 256, 0, stream>>>(bufB, Wa + 32768, ba + 256,
                                          Wb + 32768, bb + 256, bufB);
    // ---- final FC ----
    fc_k<<<(N_NODES + 63) / 64, 256, 0, stream>>>(bufB, fcW, fcb, out);
}

// Round 3
// 863.229 us; speedup vs baseline: 1.4241x; 1.2439x over previous
//
#include <hip/hip_runtime.h>
#include <hip/hip_bf16.h>
#include <math.h>

#define N_NODES 100000
#define N_PAD 100032   // padded row count for workspace feature buffers
#define N_EDGES 1600000
#define HID 128
#define N_CLASS 10

typedef float f32x4 __attribute__((ext_vector_type(4)));
typedef short short8 __attribute__((ext_vector_type(8)));
typedef unsigned short us4 __attribute__((ext_vector_type(4)));

// bf16 split helpers (round-to-nearest-even)
__device__ __forceinline__ unsigned short f2bf(float x) {
    unsigned u = __float_as_uint(x);
    unsigned r = u + 0x7FFF + ((u >> 16) & 1);
    return (unsigned short)(r >> 16);
}
__device__ __forceinline__ float bf2f(unsigned short h) {
    return __uint_as_float(((unsigned)h) << 16);
}
__device__ __forceinline__ float elu(float x) {
    return x > 0.f ? x : (expf(x) - 1.f);
}

// ---------------------------------------------------------------------------
// CSR build: histogram -> hierarchical exclusive scan -> fill
// ---------------------------------------------------------------------------

__global__ void count_k(const int* __restrict__ dst, int* __restrict__ cnt) {
    int e = blockIdx.x * blockDim.x + threadIdx.x;
    if (e < N_EDGES) atomicAdd(&cnt[dst[e]], 1);
}

__global__ void scan1_k(const int* __restrict__ in, int* __restrict__ out,
                        int* __restrict__ bsum) {
    __shared__ int sh[256];
    int base = blockIdx.x * 1024 + threadIdx.x * 4;
    int v[4];
    int s = 0;
#pragma unroll
    for (int i = 0; i < 4; i++) {
        int idx = base + i;
        v[i] = (idx < N_NODES) ? in[idx] : 0;
        s += v[i];
    }
    sh[threadIdx.x] = s;
    __syncthreads();
    for (int off = 1; off < 256; off <<= 1) {
        int t = (threadIdx.x >= off) ? sh[threadIdx.x - off] : 0;
        __syncthreads();
        sh[threadIdx.x] += t;
        __syncthreads();
    }
    int excl = sh[threadIdx.x] - s;
    if (threadIdx.x == 255) bsum[blockIdx.x] = sh[255];
    int run = excl;
#pragma unroll
    for (int i = 0; i < 4; i++) {
        int idx = base + i;
        if (idx < N_NODES) out[idx] = run;
        run += v[i];
    }
}

__global__ void scan2_k(int* __restrict__ bsum, int nb) {
    __shared__ int sh[256];
    int v = (threadIdx.x < nb) ? bsum[threadIdx.x] : 0;
    sh[threadIdx.x] = v;
    __syncthreads();
    for (int off = 1; off < 256; off <<= 1) {
        int t = (threadIdx.x >= off) ? sh[threadIdx.x - off] : 0;
        __syncthreads();
        sh[threadIdx.x] += t;
        __syncthreads();
    }
    if (threadIdx.x < nb) bsum[threadIdx.x] = sh[threadIdx.x] - v;  // exclusive
}

__global__ void scan3_k(int* __restrict__ row_ptr, const int* __restrict__ bsum,
                        int* __restrict__ cursor) {
    int i = blockIdx.x * blockDim.x + threadIdx.x;
    if (i < N_NODES) {
        int v = row_ptr[i] + bsum[i >> 10];
        row_ptr[i] = v;
        cursor[i] = v;
    }
    if (i == 0) row_ptr[N_NODES] = N_EDGES;
}

__global__ void fill_k(const int* __restrict__ src, const int* __restrict__ dst,
                       int* __restrict__ cursor, int* __restrict__ col) {
    int e = blockIdx.x * blockDim.x + threadIdx.x;
    if (e < N_EDGES) {
        int d = dst[e];
        int slot = atomicAdd(&cursor[d], 1);
        col[slot] = src[e];
    }
}

// ---------------------------------------------------------------------------
// Weight pre-split + pre-pack into MFMA B-fragment order.
// For 16x16x32 bf16: B-frag tile (nt, kb): lane L holds
//   B[k = kb*32 + (L>>4)*8 + j][n = nt*16 + (L&15)], j=0..7 contiguous.
// packed index: ((kb*8 + nt)*64 + L)*8 + j  within one 128x128 matrix.
// 6 matrices: g = layer*2 + {0=Wa, 1=Wb}.
// ---------------------------------------------------------------------------
__global__ void wsplit_k(const float* __restrict__ Wa, const float* __restrict__ Wb,
                         unsigned short* __restrict__ Whp,
                         unsigned short* __restrict__ Wlp) {
    int f = blockIdx.x * blockDim.x + threadIdx.x;
    if (f >= 6 * 16384) return;
    int g = f >> 14;
    int r = f & 16383;
    int j = r & 7;
    int L = (r >> 3) & 63;
    int t = r >> 9;          // kb*8 + nt
    int kb = t >> 3, nt = t & 7;
    int k = kb * 32 + ((L >> 4) & 3) * 8 + j;
    int n = nt * 16 + (L & 15);
    int layer = g >> 1;
    const float* W = (g & 1) ? Wb : Wa;
    float w = W[layer * 16384 + k * 128 + n];
    unsigned short hi = f2bf(w);
    unsigned short lo = f2bf(w - bf2f(hi));
    Whp[f] = hi;
    Wlp[f] = lo;
}

// ---------------------------------------------------------------------------
// Aggregation: one HALF-WAVE (32 lanes) per node, float4 per lane.
// ---------------------------------------------------------------------------
__global__ __launch_bounds__(256) void agg_k(const float* __restrict__ h,
                                             const int* __restrict__ row_ptr,
                                             const int* __restrict__ col,
                                             float* __restrict__ z) {
    const int half = (blockIdx.x * blockDim.x + threadIdx.x) >> 5;  // node id
    const int lane = threadIdx.x & 31;
    const int halfbase = threadIdx.x & 32;
    if (half >= N_NODES) return;
    const float4* hp = (const float4*)h;
    float4 acc = hp[(size_t)half * 32 + lane];  // self term, (1+eps)=1
    const int beg = row_ptr[half];
    const int end = row_ptr[half + 1];

    for (int base = beg; base < end; base += 32) {
        const int n = min(32, end - base);
        int myidx = (lane < n) ? col[base + lane] : 0;
        int j = 0;
        for (; j + 4 <= n; j += 4) {
            int i0 = __shfl(myidx, halfbase + j + 0, 64);
            int i1 = __shfl(myidx, halfbase + j + 1, 64);
            int i2 = __shfl(myidx, halfbase + j + 2, 64);
            int i3 = __shfl(myidx, halfbase + j + 3, 64);
            float4 v0 = hp[(size_t)i0 * 32 + lane];
            float4 v1 = hp[(size_t)i1 * 32 + lane];
            float4 v2 = hp[(size_t)i2 * 32 + lane];
            float4 v3 = hp[(size_t)i3 * 32 + lane];
            acc.x += v0.x; acc.y += v0.y; acc.z += v0.z; acc.w += v0.w;
            acc.x += v1.x; acc.y += v1.y; acc.z += v1.z; acc.w += v1.w;
            acc.x += v2.x; acc.y += v2.y; acc.z += v2.z; acc.w += v2.w;
            acc.x += v3.x; acc.y += v3.y; acc.z += v3.z; acc.w += v3.w;
        }
        for (; j < n; j++) {
            int i0 = __shfl(myidx, halfbase + j, 64);
            float4 v0 = hp[(size_t)i0 * 32 + lane];
            acc.x += v0.x; acc.y += v0.y; acc.z += v0.z; acc.w += v0.w;
        }
    }
    ((float4*)z)[(size_t)half * 32 + lane] = acc;
}

// ---------------------------------------------------------------------------
// MFMA MLP: h_out = ELU(ELU(z@Wa + ba)@Wb + bb), split-bf16 x3 terms.
// 64 nodes/block, 4 waves. Wave w: M-tiles {2(w>>1), 2(w>>1)+1},
// N-tiles {4(w&1)..4(w&1)+3}. A hi/lo + W-hi in LDS (64 KB), W-lo from L2.
// ---------------------------------------------------------------------------
__device__ __forceinline__ void gemm_phase(
    const unsigned short* Aph_, const unsigned short* Apl_,
    const unsigned short* Wph_, const unsigned short* __restrict__ Wlo_g,
    const float* __restrict__ bias, int tid, f32x4 acc[2][4]) {
    const int L = tid & 63;
    const int w = tid >> 6;
    const int mt0 = (w >> 1) * 2;
    const int nt0 = (w & 1) * 4;
    const int lan15 = L & 15;
#pragma unroll
    for (int n = 0; n < 4; n++) {
        float b = bias[(nt0 + n) * 16 + lan15];
        f32x4 bv = {b, b, b, b};
        acc[0][n] = bv;
        acc[1][n] = bv;
    }
#pragma unroll
    for (int kb = 0; kb < 4; kb++) {
        short8 ah0 = *(const short8*)&Aph_[(((mt0 + 0) * 4 + kb) * 64 + L) * 8];
        short8 ah1 = *(const short8*)&Aph_[(((mt0 + 1) * 4 + kb) * 64 + L) * 8];
        short8 al0 = *(const short8*)&Apl_[(((mt0 + 0) * 4 + kb) * 64 + L) * 8];
        short8 al1 = *(const short8*)&Apl_[(((mt0 + 1) * 4 + kb) * 64 + L) * 8];
#pragma unroll
        for (int n = 0; n < 4; n++) {
            int widx = ((kb * 8 + nt0 + n) * 64 + L) * 8;
            short8 bh = *(const short8*)&Wph_[widx];
            short8 bl = *(const short8*)&Wlo_g[widx];
            acc[0][n] = __builtin_amdgcn_mfma_f32_16x16x32_bf16(ah0, bh, acc[0][n], 0, 0, 0);
            acc[1][n] = __builtin_amdgcn_mfma_f32_16x16x32_bf16(ah1, bh, acc[1][n], 0, 0, 0);
            acc[0][n] = __builtin_amdgcn_mfma_f32_16x16x32_bf16(al0, bh, acc[0][n], 0, 0, 0);
            acc[1][n] = __builtin_amdgcn_mfma_f32_16x16x32_bf16(al1, bh, acc[1][n], 0, 0, 0);
            acc[0][n] = __builtin_amdgcn_mfma_f32_16x16x32_bf16(ah0, bl, acc[0][n], 0, 0, 0);
            acc[1][n] = __builtin_amdgcn_mfma_f32_16x16x32_bf16(ah1, bl, acc[1][n], 0, 0, 0);
        }
    }
}

__global__ __launch_bounds__(256) void mlp2_k(
    const float* __restrict__ zin,
    const unsigned short* __restrict__ Wahp, const unsigned short* __restrict__ Walp,
    const unsigned short* __restrict__ Wbhp, const unsigned short* __restrict__ Wblp,
    const float* __restrict__ ba, const float* __restrict__ bb,
    float* __restrict__ hout) {
    __shared__ unsigned short Aph[8192];   // 16 KB: packed A hi
    __shared__ unsigned short Apl[8192];   // 16 KB: packed A lo
    __shared__ unsigned short Wph[16384];  // 32 KB: packed W hi

    const int tid = threadIdx.x;
    const int L = tid & 63;
    const int w = tid >> 6;
    const int mt0 = (w >> 1) * 2;
    const int nt0 = (w & 1) * 4;
    const int lan15 = L & 15;
    const int quad = L >> 4;
    const size_t node_base = (size_t)blockIdx.x * 64;

    // ---- phase A: load z tile, split to bf16 hi/lo, pack to A-frag layout;
    //      stage Wa-hi into LDS ----
    {
        const float4* zin4 = (const float4*)(zin + node_base * HID);
#pragma unroll
        for (int r = 0; r < 8; r++) {
            int f = tid + 256 * r;          // [0, 2048)
            int m = f >> 5;
            int k0 = (f & 31) * 4;
            float4 zv = zin4[f];
            int kb = k0 >> 5;
            int q = (k0 & 31) >> 3;
            int j0 = k0 & 7;                 // 0 or 4
            int idx = (((m >> 4) * 4 + kb) * 64 + ((m & 15) + 16 * q)) * 8 + j0;
            unsigned short hx = f2bf(zv.x), hy = f2bf(zv.y),
                           hz = f2bf(zv.z), hw = f2bf(zv.w);
            us4 h4 = {hx, hy, hz, hw};
            us4 l4 = {f2bf(zv.x - bf2f(hx)), f2bf(zv.y - bf2f(hy)),
                      f2bf(zv.z - bf2f(hz)), f2bf(zv.w - bf2f(hw))};
            *(us4*)&Aph[idx] = h4;
            *(us4*)&Apl[idx] = l4;
        }
        const uint4* wsrc = (const uint4*)Wahp;
        uint4* wdst = (uint4*)Wph;
#pragma unroll
        for (int r = 0; r < 8; r++) wdst[tid + 256 * r] = wsrc[tid + 256 * r];
    }
    __syncthreads();

    // ---- GEMM1: t = ELU(z @ Wa + ba) ----
    {
        f32x4 acc[2][4];
        gemm_phase(Aph, Apl, Wph, Walp, ba, tid, acc);
        __syncthreads();  // all waves done reading A/W frags
        // epilogue: ELU, split, repack into A-frag layout for GEMM2
#pragma unroll
        for (int i = 0; i < 2; i++) {
#pragma unroll
            for (int n = 0; n < 4; n++) {
                int kdim = (nt0 + n) * 16 + lan15;
                int kb2 = kdim >> 5;
                int q2 = (kdim & 31) >> 3;
                int j2 = kdim & 7;
#pragma unroll
                for (int r = 0; r < 3 + 1; r++) {
                    float v = elu(acc[i][n][r]);
                    int mrow = quad * 4 + r;  // m & 15 within tile mt0+i
                    unsigned short hi = f2bf(v);
                    unsigned short lo = f2bf(v - bf2f(hi));
                    int idx = (((mt0 + i) * 4 + kb2) * 64 + (mrow + 16 * q2)) * 8 + j2;
                    Aph[idx] = hi;
                    Apl[idx] = lo;
                }
            }
        }
        // stage Wb-hi
        const uint4* wsrc = (const uint4*)Wbhp;
        uint4* wdst = (uint4*)Wph;
#pragma unroll
        for (int r = 0; r < 8; r++) wdst[tid + 256 * r] = wsrc[tid + 256 * r];
    }
    __syncthreads();

    // ---- GEMM2: h = ELU(t @ Wb + bb), direct global store ----
    {
        f32x4 acc[2][4];
        gemm_phase(Aph, Apl, Wph, Wblp, bb, tid, acc);
#pragma unroll
        for (int i = 0; i < 2; i++) {
#pragma unroll
            for (int n = 0; n < 4; n++) {
                int ncol = (nt0 + n) * 16 + lan15;
#pragma unroll
                for (int r = 0; r < 4; r++) {
                    int mrow = (mt0 + i) * 16 + quad * 4 + r;
                    hout[(node_base + mrow) * HID + ncol] = elu(acc[i][n][r]);
                }
            }
        }
    }
}

// ---------------------------------------------------------------------------
// Final FC: out = h @ fcW + fcb   [100k x 10]
// ---------------------------------------------------------------------------
__global__ __launch_bounds__(256) void fc_k(const float* __restrict__ h,
                                            const float* __restrict__ fcW,
                                            const float* __restrict__ fcb,
                                            float* __restrict__ out) {
    __shared__ float ht[64][HID + 4];
    size_t nb = (size_t)blockIdx.x * 64;
#pragma unroll
    for (int r = 0; r < 8; r++) {
        int off = r * 1024 + threadIdx.x * 4;
        int row = off >> 7, colo = off & 127;
        if (nb + row < N_NODES)
            *(float4*)&ht[row][colo] = *(const float4*)&h[(nb + row) * HID + colo];
    }
    __syncthreads();
    for (int o = threadIdx.x; o < 64 * N_CLASS; o += 256) {
        int n = o / N_CLASS, c = o % N_CLASS;
        if (nb + n < N_NODES) {
            float acc = fcb[c];
            for (int k = 0; k < HID; k++) acc += ht[n][k] * fcW[k * N_CLASS + c];
            out[(nb + n) * N_CLASS + c] = acc;
        }
    }
}

// ---------------------------------------------------------------------------

extern "C" void kernel_launch(void* const* d_in, const int* in_sizes, int n_in,
                              void* d_out, int out_size, void* d_ws, size_t ws_size,
                              hipStream_t stream) {
    const float* x = (const float*)d_in[0];
    const int* ei = (const int*)d_in[1];  // [2][E]
    // d_in[2] = edge_weight (unused by the reference forward)
    const float* Wa = (const float*)d_in[3];   // [3][128][128]
    const float* ba = (const float*)d_in[4];   // [3][128]
    const float* Wb = (const float*)d_in[5];
    const float* bb = (const float*)d_in[6];
    const float* fcW = (const float*)d_in[7];  // [128][10]
    const float* fcb = (const float*)d_in[8];  // [10]
    float* out = (float*)d_out;

    const int* src = ei;
    const int* dst = ei + N_EDGES;

    // workspace carve
    char* w = (char*)d_ws;
    float* bufA = (float*)w; w += (size_t)N_PAD * HID * 4;
    float* bufB = (float*)w; w += (size_t)N_PAD * HID * 4;
    int* row_ptr = (int*)w;  w += ((size_t)N_NODES + 8) * 4;
    int* cursor = (int*)w;   w += (size_t)N_NODES * 4;
    int* col = (int*)w;      w += (size_t)N_EDGES * 4;
    int* bsum = (int*)w;     w += 256 * 4;
    unsigned short* Whp = (unsigned short*)w; w += 6 * 16384 * 2;
    unsigned short* Wlp = (unsigned short*)w; w += 6 * 16384 * 2;

    const int SCAN_BLOCKS = (N_NODES + 1023) / 1024;  // 98

    // ---- weight split/pack (independent of CSR) ----
    wsplit_k<<<(6 * 16384 + 255) / 256, 256, 0, stream>>>(Wa, Wb, Whp, Wlp);

    // ---- CSR build ----
    hipMemsetAsync(cursor, 0, (size_t)N_NODES * 4, stream);
    count_k<<<N_EDGES / 256, 256, 0, stream>>>(dst, cursor);
    scan1_k<<<SCAN_BLOCKS, 256, 0, stream>>>(cursor, row_ptr, bsum);
    scan2_k<<<1, 256, 0, stream>>>(bsum, SCAN_BLOCKS);
    scan3_k<<<(N_NODES + 255) / 256, 256, 0, stream>>>(row_ptr, bsum, cursor);
    fill_k<<<N_EDGES / 256, 256, 0, stream>>>(src, dst, cursor, col);

    const int AGG_BLOCKS = (N_NODES * 32 + 255) / 256;  // one half-wave per node
    const int MLP_BLOCKS = (N_NODES + 63) / 64;         // 1563 (ws rows padded)

    // ---- layer 1: x -> bufB ----
    agg_k<<<AGG_BLOCKS, 256, 0, stream>>>(x, row_ptr, col, bufB);
    mlp2_k<<<MLP_BLOCKS, 256, 0, stream>>>(bufB, Whp, Wlp, Whp + 16384, Wlp + 16384,
                                           ba, bb, bufB);
    // ---- layer 2: bufB -> bufA ----
    agg_k<<<AGG_BLOCKS, 256, 0, stream>>>(bufB, row_ptr, col, bufA);
    mlp2_k<<<MLP_BLOCKS, 256, 0, stream>>>(bufA, Whp + 2 * 16384, Wlp + 2 * 16384,
                                           Whp + 3 * 16384, Wlp + 3 * 16384,
                                           ba + 128, bb + 128, bufA);
    // ---- layer 3: bufA -> bufB ----
    agg_k<<<AGG_BLOCKS, 256, 0, stream>>>(bufA, row_ptr, col, bufB);
    mlp2_k<<<MLP_BLOCKS, 256, 0, stream>>>(bufB, Whp + 4 * 16384, Wlp + 4 * 16384,
                                           Whp + 5 * 16384, Wlp + 5 * 16384,
                                           ba + 256, bb + 256, bufB);
    // ---- final FC ----
    fc_k<<<(N_NODES + 63) / 64, 256, 0, stream>>>(bufB, fcW, fcb, out);
}

// Round 4
// 626.377 us; speedup vs baseline: 1.9626x; 1.3781x over previous
//
#include <hip/hip_runtime.h>
#include <hip/hip_bf16.h>
#include <math.h>

#define N_NODES 100000
#define N_PAD 100032   // padded row count for workspace feature buffers
#define N_EDGES 1600000
#define HID 128
#define N_CLASS 10

typedef float f32x4 __attribute__((ext_vector_type(4)));
typedef short short8 __attribute__((ext_vector_type(8)));
typedef unsigned short us4 __attribute__((ext_vector_type(4)));

// bf16 helpers (round-to-nearest-even)
__device__ __forceinline__ unsigned short f2bf(float x) {
    unsigned u = __float_as_uint(x);
    unsigned r = u + 0x7FFF + ((u >> 16) & 1);
    return (unsigned short)(r >> 16);
}
__device__ __forceinline__ float bf2f(unsigned short h) {
    return __uint_as_float(((unsigned)h) << 16);
}
__device__ __forceinline__ float elu(float x) {
    return x > 0.f ? x : (expf(x) - 1.f);
}

// ---------------------------------------------------------------------------
// CSR build: histogram -> hierarchical exclusive scan -> XCD-partitioned fill
// ---------------------------------------------------------------------------

__global__ void count_k(const int* __restrict__ dst, int* __restrict__ cnt) {
    int e = blockIdx.x * blockDim.x + threadIdx.x;
    if (e < N_EDGES) atomicAdd(&cnt[dst[e]], 1);
}

__global__ void scan1_k(const int* __restrict__ in, int* __restrict__ out,
                        int* __restrict__ bsum) {
    __shared__ int sh[256];
    int base = blockIdx.x * 1024 + threadIdx.x * 4;
    int v[4];
    int s = 0;
#pragma unroll
    for (int i = 0; i < 4; i++) {
        int idx = base + i;
        v[i] = (idx < N_NODES) ? in[idx] : 0;
        s += v[i];
    }
    sh[threadIdx.x] = s;
    __syncthreads();
    for (int off = 1; off < 256; off <<= 1) {
        int t = (threadIdx.x >= off) ? sh[threadIdx.x - off] : 0;
        __syncthreads();
        sh[threadIdx.x] += t;
        __syncthreads();
    }
    int excl = sh[threadIdx.x] - s;
    if (threadIdx.x == 255) bsum[blockIdx.x] = sh[255];
    int run = excl;
#pragma unroll
    for (int i = 0; i < 4; i++) {
        int idx = base + i;
        if (idx < N_NODES) out[idx] = run;
        run += v[i];
    }
}

__global__ void scan2_k(int* __restrict__ bsum, int nb) {
    __shared__ int sh[256];
    int v = (threadIdx.x < nb) ? bsum[threadIdx.x] : 0;
    sh[threadIdx.x] = v;
    __syncthreads();
    for (int off = 1; off < 256; off <<= 1) {
        int t = (threadIdx.x >= off) ? sh[threadIdx.x - off] : 0;
        __syncthreads();
        sh[threadIdx.x] += t;
        __syncthreads();
    }
    if (threadIdx.x < nb) bsum[threadIdx.x] = sh[threadIdx.x] - v;  // exclusive
}

__global__ void scan3_k(int* __restrict__ row_ptr, const int* __restrict__ bsum,
                        int* __restrict__ cursor) {
    int i = blockIdx.x * blockDim.x + threadIdx.x;
    if (i < N_NODES) {
        int v = row_ptr[i] + bsum[i >> 10];
        row_ptr[i] = v;
        cursor[i] = v;
    }
    if (i == 0) row_ptr[N_NODES] = N_EDGES;
}

// XCD-partitioned fill: block b handles only dst in range (b&7); consecutive
// blockIdx round-robin across XCDs, so each col cacheline is written by one
// XCD's L2 -> writebacks merge (was 16x write amplification).
#define FILL_SLICES 256
#define DST_RANGE 12512  // 8 * 12512 >= N_NODES
__global__ __launch_bounds__(256) void fill_k(const int* __restrict__ src,
                                              const int* __restrict__ dst,
                                              int* __restrict__ cursor,
                                              int* __restrict__ col) {
    const int xcd = blockIdx.x & 7;
    const int slice = blockIdx.x >> 3;
    const int lo = xcd * DST_RANGE;
    const int hi = lo + DST_RANGE;
    const int e0 = slice * (N_EDGES / FILL_SLICES);
    const int e1 = e0 + (N_EDGES / FILL_SLICES);
    for (int e = e0 + threadIdx.x; e < e1; e += 256) {
        int d = dst[e];
        if (d >= lo && d < hi) {
            int slot = atomicAdd(&cursor[d], 1);
            col[slot] = src[e];
        }
    }
}

// ---------------------------------------------------------------------------
// fp32 -> bf16 cast of x (layer-1 gather source)
// ---------------------------------------------------------------------------
__global__ __launch_bounds__(256) void cast_k(const float* __restrict__ x,
                                              unsigned short* __restrict__ hb) {
    int i = blockIdx.x * blockDim.x + threadIdx.x;  // float4 index
    if (i < N_NODES * (HID / 4)) {
        float4 v = ((const float4*)x)[i];
        us4 o = {f2bf(v.x), f2bf(v.y), f2bf(v.z), f2bf(v.w)};
        ((us4*)hb)[i] = o;
    }
}

// ---------------------------------------------------------------------------
// Weight pre-split + pre-pack into MFMA B-fragment order (see round 3).
// ---------------------------------------------------------------------------
__global__ void wsplit_k(const float* __restrict__ Wa, const float* __restrict__ Wb,
                         unsigned short* __restrict__ Whp,
                         unsigned short* __restrict__ Wlp) {
    int f = blockIdx.x * blockDim.x + threadIdx.x;
    if (f >= 6 * 16384) return;
    int g = f >> 14;
    int r = f & 16383;
    int j = r & 7;
    int L = (r >> 3) & 63;
    int t = r >> 9;          // kb*8 + nt
    int kb = t >> 3, nt = t & 7;
    int k = kb * 32 + ((L >> 4) & 3) * 8 + j;
    int n = nt * 16 + (L & 15);
    int layer = g >> 1;
    const float* W = (g & 1) ? Wb : Wa;
    float w = W[layer * 16384 + k * 128 + n];
    unsigned short hi = f2bf(w);
    unsigned short lo = f2bf(w - bf2f(hi));
    Whp[f] = hi;
    Wlp[f] = lo;
}

// ---------------------------------------------------------------------------
// Aggregation: one HALF-WAVE (32 lanes) per node, bf16 rows (256B), us4/lane.
// fp32 accumulate. z[n] = h[n] + sum_{s in N(n)} h[s]
// ---------------------------------------------------------------------------
__device__ __forceinline__ float4 us4f(us4 v) {
    float4 o;
    o.x = bf2f(v.x); o.y = bf2f(v.y); o.z = bf2f(v.z); o.w = bf2f(v.w);
    return o;
}

__global__ __launch_bounds__(256) void agg_k(const unsigned short* __restrict__ h,
                                             const int* __restrict__ row_ptr,
                                             const int* __restrict__ col,
                                             float* __restrict__ z) {
    const int half = (blockIdx.x * blockDim.x + threadIdx.x) >> 5;  // node id
    const int lane = threadIdx.x & 31;
    const int halfbase = threadIdx.x & 32;
    if (half >= N_NODES) return;
    const us4* hp = (const us4*)h;  // 32 x us4 per row
    float4 acc = us4f(hp[(size_t)half * 32 + lane]);  // self term, (1+eps)=1
    const int beg = row_ptr[half];
    const int end = row_ptr[half + 1];

    for (int base = beg; base < end; base += 32) {
        const int n = min(32, end - base);
        int myidx = (lane < n) ? col[base + lane] : 0;
        int j = 0;
        for (; j + 4 <= n; j += 4) {
            int i0 = __shfl(myidx, halfbase + j + 0, 64);
            int i1 = __shfl(myidx, halfbase + j + 1, 64);
            int i2 = __shfl(myidx, halfbase + j + 2, 64);
            int i3 = __shfl(myidx, halfbase + j + 3, 64);
            float4 v0 = us4f(hp[(size_t)i0 * 32 + lane]);
            float4 v1 = us4f(hp[(size_t)i1 * 32 + lane]);
            float4 v2 = us4f(hp[(size_t)i2 * 32 + lane]);
            float4 v3 = us4f(hp[(size_t)i3 * 32 + lane]);
            acc.x += v0.x; acc.y += v0.y; acc.z += v0.z; acc.w += v0.w;
            acc.x += v1.x; acc.y += v1.y; acc.z += v1.z; acc.w += v1.w;
            acc.x += v2.x; acc.y += v2.y; acc.z += v2.z; acc.w += v2.w;
            acc.x += v3.x; acc.y += v3.y; acc.z += v3.z; acc.w += v3.w;
        }
        for (; j < n; j++) {
            int i0 = __shfl(myidx, halfbase + j, 64);
            float4 v0 = us4f(hp[(size_t)i0 * 32 + lane]);
            acc.x += v0.x; acc.y += v0.y; acc.z += v0.z; acc.w += v0.w;
        }
    }
    ((float4*)z)[(size_t)half * 32 + lane] = acc;  // fp32 out, 32 float4/row
}

// ---------------------------------------------------------------------------
// MFMA MLP: h_out(bf16) = ELU(ELU(z@Wa + ba)@Wb + bb), split-bf16 x3 terms.
// ---------------------------------------------------------------------------
__device__ __forceinline__ void gemm_phase(
    const unsigned short* Aph_, const unsigned short* Apl_,
    const unsigned short* Wph_, const unsigned short* __restrict__ Wlo_g,
    const float* __restrict__ bias, int tid, f32x4 acc[2][4]) {
    const int L = tid & 63;
    const int w = tid >> 6;
    const int mt0 = (w >> 1) * 2;
    const int nt0 = (w & 1) * 4;
    const int lan15 = L & 15;
#pragma unroll
    for (int n = 0; n < 4; n++) {
        float b = bias[(nt0 + n) * 16 + lan15];
        f32x4 bv = {b, b, b, b};
        acc[0][n] = bv;
        acc[1][n] = bv;
    }
#pragma unroll
    for (int kb = 0; kb < 4; kb++) {
        short8 ah0 = *(const short8*)&Aph_[(((mt0 + 0) * 4 + kb) * 64 + L) * 8];
        short8 ah1 = *(const short8*)&Aph_[(((mt0 + 1) * 4 + kb) * 64 + L) * 8];
        short8 al0 = *(const short8*)&Apl_[(((mt0 + 0) * 4 + kb) * 64 + L) * 8];
        short8 al1 = *(const short8*)&Apl_[(((mt0 + 1) * 4 + kb) * 64 + L) * 8];
#pragma unroll
        for (int n = 0; n < 4; n++) {
            int widx = ((kb * 8 + nt0 + n) * 64 + L) * 8;
            short8 bh = *(const short8*)&Wph_[widx];
            short8 bl = *(const short8*)&Wlo_g[widx];
            acc[0][n] = __builtin_amdgcn_mfma_f32_16x16x32_bf16(ah0, bh, acc[0][n], 0, 0, 0);
            acc[1][n] = __builtin_amdgcn_mfma_f32_16x16x32_bf16(ah1, bh, acc[1][n], 0, 0, 0);
            acc[0][n] = __builtin_amdgcn_mfma_f32_16x16x32_bf16(al0, bh, acc[0][n], 0, 0, 0);
            acc[1][n] = __builtin_amdgcn_mfma_f32_16x16x32_bf16(al1, bh, acc[1][n], 0, 0, 0);
            acc[0][n] = __builtin_amdgcn_mfma_f32_16x16x32_bf16(ah0, bl, acc[0][n], 0, 0, 0);
            acc[1][n] = __builtin_amdgcn_mfma_f32_16x16x32_bf16(ah1, bl, acc[1][n], 0, 0, 0);
        }
    }
}

__global__ __launch_bounds__(256) void mlp2_k(
    const float* __restrict__ zin,
    const unsigned short* __restrict__ Wahp, const unsigned short* __restrict__ Walp,
    const unsigned short* __restrict__ Wbhp, const unsigned short* __restrict__ Wblp,
    const float* __restrict__ ba, const float* __restrict__ bb,
    unsigned short* __restrict__ hout) {
    __shared__ unsigned short Aph[8192];   // 16 KB: packed A hi
    __shared__ unsigned short Apl[8192];   // 16 KB: packed A lo
    __shared__ unsigned short Wph[16384];  // 32 KB: packed W hi

    const int tid = threadIdx.x;
    const int L = tid & 63;
    const int w = tid >> 6;
    const int mt0 = (w >> 1) * 2;
    const int nt0 = (w & 1) * 4;
    const int lan15 = L & 15;
    const int quad = L >> 4;
    const size_t node_base = (size_t)blockIdx.x * 64;

    // ---- phase A: load z tile, split to bf16 hi/lo, pack to A-frag layout;
    //      stage Wa-hi into LDS ----
    {
        const float4* zin4 = (const float4*)(zin + node_base * HID);
#pragma unroll
        for (int r = 0; r < 8; r++) {
            int f = tid + 256 * r;          // [0, 2048)
            int m = f >> 5;
            int k0 = (f & 31) * 4;
            float4 zv = zin4[f];
            int kb = k0 >> 5;
            int q = (k0 & 31) >> 3;
            int j0 = k0 & 7;                 // 0 or 4
            int idx = (((m >> 4) * 4 + kb) * 64 + ((m & 15) + 16 * q)) * 8 + j0;
            unsigned short hx = f2bf(zv.x), hy = f2bf(zv.y),
                           hz = f2bf(zv.z), hw = f2bf(zv.w);
            us4 h4 = {hx, hy, hz, hw};
            us4 l4 = {f2bf(zv.x - bf2f(hx)), f2bf(zv.y - bf2f(hy)),
                      f2bf(zv.z - bf2f(hz)), f2bf(zv.w - bf2f(hw))};
            *(us4*)&Aph[idx] = h4;
            *(us4*)&Apl[idx] = l4;
        }
        const uint4* wsrc = (const uint4*)Wahp;
        uint4* wdst = (uint4*)Wph;
#pragma unroll
        for (int r = 0; r < 8; r++) wdst[tid + 256 * r] = wsrc[tid + 256 * r];
    }
    __syncthreads();

    // ---- GEMM1: t = ELU(z @ Wa + ba) ----
    {
        f32x4 acc[2][4];
        gemm_phase(Aph, Apl, Wph, Walp, ba, tid, acc);
        __syncthreads();  // all waves done reading A/W frags
#pragma unroll
        for (int i = 0; i < 2; i++) {
#pragma unroll
            for (int n = 0; n < 4; n++) {
                int kdim = (nt0 + n) * 16 + lan15;
                int kb2 = kdim >> 5;
                int q2 = (kdim & 31) >> 3;
                int j2 = kdim & 7;
#pragma unroll
                for (int r = 0; r < 4; r++) {
                    float v = elu(acc[i][n][r]);
                    int mrow = quad * 4 + r;
                    unsigned short hi = f2bf(v);
                    unsigned short lo = f2bf(v - bf2f(hi));
                    int idx = (((mt0 + i) * 4 + kb2) * 64 + (mrow + 16 * q2)) * 8 + j2;
                    Aph[idx] = hi;
                    Apl[idx] = lo;
                }
            }
        }
        const uint4* wsrc = (const uint4*)Wbhp;
        uint4* wdst = (uint4*)Wph;
#pragma unroll
        for (int r = 0; r < 8; r++) wdst[tid + 256 * r] = wsrc[tid + 256 * r];
    }
    __syncthreads();

    // ---- GEMM2: h = ELU(t @ Wb + bb), bf16 store ----
    {
        f32x4 acc[2][4];
        gemm_phase(Aph, Apl, Wph, Wblp, bb, tid, acc);
#pragma unroll
        for (int i = 0; i < 2; i++) {
#pragma unroll
            for (int n = 0; n < 4; n++) {
                int ncol = (nt0 + n) * 16 + lan15;
#pragma unroll
                for (int r = 0; r < 4; r++) {
                    int mrow = (mt0 + i) * 16 + quad * 4 + r;
                    hout[(node_base + mrow) * HID + ncol] = f2bf(elu(acc[i][n][r]));
                }
            }
        }
    }
}

// ---------------------------------------------------------------------------
// Final FC: out = h(bf16) @ fcW + fcb   [100k x 10]
// ---------------------------------------------------------------------------
__global__ __launch_bounds__(256) void fc_k(const unsigned short* __restrict__ h,
                                            const float* __restrict__ fcW,
                                            const float* __restrict__ fcb,
                                            float* __restrict__ out) {
    __shared__ float ht[64][HID + 4];
    size_t nb = (size_t)blockIdx.x * 64;
#pragma unroll
    for (int r = 0; r < 8; r++) {
        int off = r * 1024 + threadIdx.x * 4;
        int row = off >> 7, colo = off & 127;
        if (nb + row < N_NODES) {
            us4 v = *(const us4*)&h[(nb + row) * HID + colo];
            ht[row][colo + 0] = bf2f(v.x);
            ht[row][colo + 1] = bf2f(v.y);
            ht[row][colo + 2] = bf2f(v.z);
            ht[row][colo + 3] = bf2f(v.w);
        }
    }
    __syncthreads();
    for (int o = threadIdx.x; o < 64 * N_CLASS; o += 256) {
        int n = o / N_CLASS, c = o % N_CLASS;
        if (nb + n < N_NODES) {
            float acc = fcb[c];
            for (int k = 0; k < HID; k++) acc += ht[n][k] * fcW[k * N_CLASS + c];
            out[(nb + n) * N_CLASS + c] = acc;
        }
    }
}

// ---------------------------------------------------------------------------

extern "C" void kernel_launch(void* const* d_in, const int* in_sizes, int n_in,
                              void* d_out, int out_size, void* d_ws, size_t ws_size,
                              hipStream_t stream) {
    const float* x = (const float*)d_in[0];
    const int* ei = (const int*)d_in[1];  // [2][E]
    // d_in[2] = edge_weight (unused by the reference forward)
    const float* Wa = (const float*)d_in[3];   // [3][128][128]
    const float* ba = (const float*)d_in[4];   // [3][128]
    const float* Wb = (const float*)d_in[5];
    const float* bb = (const float*)d_in[6];
    const float* fcW = (const float*)d_in[7];  // [128][10]
    const float* fcb = (const float*)d_in[8];  // [10]
    float* out = (float*)d_out;

    const int* src = ei;
    const int* dst = ei + N_EDGES;

    // workspace carve
    char* w = (char*)d_ws;
    float* zbuf = (float*)w;          w += (size_t)N_PAD * HID * 4;  // fp32 agg out
    unsigned short* hb = (unsigned short*)w; w += (size_t)N_PAD * HID * 2;  // bf16 h
    int* row_ptr = (int*)w;  w += ((size_t)N_NODES + 8) * 4;
    int* cursor = (int*)w;   w += (size_t)N_NODES * 4;
    int* col = (int*)w;      w += (size_t)N_EDGES * 4;
    int* bsum = (int*)w;     w += 256 * 4;
    unsigned short* Whp = (unsigned short*)w; w += 6 * 16384 * 2;
    unsigned short* Wlp = (unsigned short*)w; w += 6 * 16384 * 2;

    const int SCAN_BLOCKS = (N_NODES + 1023) / 1024;  // 98

    // ---- weight split/pack + x cast (independent of CSR) ----
    wsplit_k<<<(6 * 16384 + 255) / 256, 256, 0, stream>>>(Wa, Wb, Whp, Wlp);
    cast_k<<<(N_NODES * (HID / 4) + 255) / 256, 256, 0, stream>>>(x, hb);

    // ---- CSR build ----
    hipMemsetAsync(cursor, 0, (size_t)N_NODES * 4, stream);
    count_k<<<N_EDGES / 256, 256, 0, stream>>>(dst, cursor);
    scan1_k<<<SCAN_BLOCKS, 256, 0, stream>>>(cursor, row_ptr, bsum);
    scan2_k<<<1, 256, 0, stream>>>(bsum, SCAN_BLOCKS);
    scan3_k<<<(N_NODES + 255) / 256, 256, 0, stream>>>(row_ptr, bsum, cursor);
    fill_k<<<FILL_SLICES * 8, 256, 0, stream>>>(src, dst, cursor, col);

    const int AGG_BLOCKS = (N_NODES * 32 + 255) / 256;  // one half-wave per node
    const int MLP_BLOCKS = (N_NODES + 63) / 64;         // 1563 (ws rows padded)

    // ---- layer 1 ----
    agg_k<<<AGG_BLOCKS, 256, 0, stream>>>(hb, row_ptr, col, zbuf);
    mlp2_k<<<MLP_BLOCKS, 256, 0, stream>>>(zbuf, Whp, Wlp, Whp + 16384, Wlp + 16384,
                                           ba, bb, hb);
    // ---- layer 2 ----
    agg_k<<<AGG_BLOCKS, 256, 0, stream>>>(hb, row_ptr, col, zbuf);
    mlp2_k<<<MLP_BLOCKS, 256, 0, stream>>>(zbuf, Whp + 2 * 16384, Wlp + 2 * 16384,
                                           Whp + 3 * 16384, Wlp + 3 * 16384,
                                           ba + 128, bb + 128, hb);
    // ---- layer 3 ----
    agg_k<<<AGG_BLOCKS, 256, 0, stream>>>(hb, row_ptr, col, zbuf);
    mlp2_k<<<MLP_BLOCKS, 256, 0, stream>>>(zbuf, Whp + 4 * 16384, Wlp + 4 * 16384,
                                           Whp + 5 * 16384, Wlp + 5 * 16384,
                                           ba + 256, bb + 256, hb);
    // ---- final FC ----
    fc_k<<<(N_NODES + 63) / 64, 256, 0, stream>>>(hb, fcW, fcb, out);
}